// Round 4
// baseline (162.239 us; speedup 1.0000x reference)
//
#include <hip/hip_runtime.h>
#include <math.h>

#define A_ 5
#define C_ 20
#define N_ 64
#define H_ 52
#define W_ 52
#define HW_ (H_ * W_)        // 2704
#define M_ 32
#define CH_ (A_ * (5 + C_))  // 125
#define PAIRS (N_ * A_ * HW_)            // 865,280 (cell,anchor) pairs
#define CPB_A 64
#define NBX_A ((HW_ + CPB_A - 1) / CPB_A)  // 43
#define CPB_B 256
#define NBX_B ((HW_ + CPB_B - 1) / CPB_B)  // 11
#define NBLK_B (NBX_B * N_)                // 704
// ws layout (floats): [0..4)*PAIRS = bi,bu,ov,bm(bits); then 3*NBLK_B partials
#define WS_PART (4 * (size_t)PAIRS)

// ---------------- Kernel A: thread per (cell, anchor) ----------------
// 2752 blocks x 5 waves = 53 waves/CU available. No LDS, no barriers.
// Only box construction + IoU argmax (the dominant VALU cost) lives here.
__global__ __launch_bounds__(320) void yolo_pair(
    const float* __restrict__ x,       // (N, 125, H, W)
    const float* __restrict__ anchors, // (5, 2)
    const float* __restrict__ gt,      // (N, 32, 4)
    const void* img_h_p, const void* img_w_p,
    float* __restrict__ ws)
{
    const int tid  = threadIdx.x;
    const int a    = tid >> 6;          // anchor = wave id
    const int lane = tid & 63;
    const int n    = blockIdx.y;
    const int cell = blockIdx.x * CPB_A + lane;
    if (cell >= HW_) return;

    int ibw = *(const int*)img_w_p;
    float img_w = (ibw > 0 && ibw < 1000000) ? (float)ibw : *(const float*)img_w_p;
    int ibh = *(const int*)img_h_p;
    float img_h = (ibh > 0 && ibh < 1000000) ? (float)ibh : *(const float*)img_h_p;
    const float sx = img_w / (float)W_;
    const float sy = img_h / (float)H_;

    const float ax = anchors[2 * a];     // wave-uniform
    const float ay = anchors[2 * a + 1];

    const int wi = cell % W_;
    const int hi = cell / W_;
    const size_t base = (size_t)n * CH_ * HW_ + (size_t)a * 25 * HW_ + cell;
    float t0 = x[base];
    float t1 = x[base + (size_t)HW_];
    float t2 = x[base + 2 * (size_t)HW_];
    float t3 = x[base + 3 * (size_t)HW_];
    float t4 = x[base + 4 * (size_t)HW_];

    float bx = 1.f / (1.f + __expf(-t0)) + (float)wi * sx;
    float by = 1.f / (1.f + __expf(-t1)) + (float)hi * sy;
    float bw = sx * ax * __expf(t2);
    float bh = sy * ay * __expf(t3);
    float x1 = bx, y1 = by, x2 = bx + bw, y2 = by + bh;
    float ov = 1.f / (1.f + __expf(-t4));
    float ap = (x2 - x1) * (y2 - y1);    // match reference exactly

    float bi = 0.f, bu = 1.f;
    int   bm = 0;
    const float4* gtv = (const float4*)(gt + (size_t)n * M_ * 4);
    #pragma unroll 8
    for (int m = 0; m < M_; ++m) {
        float4 g = gtv[m];               // uniform -> scalar load path
        float area = (g.z - g.x) * (g.w - g.y);
        float wxi = fminf(x2, g.z) - fmaxf(x1, g.x);
        float hyi = fminf(y2, g.w) - fmaxf(y1, g.y);
        wxi = fmaxf(wxi, 0.f);
        hyi = fmaxf(hyi, 0.f);
        float inter = wxi * hyi;
        float uni = ap + area - inter;
        if (inter * bu > bi * uni) { bi = inter; bu = uni; bm = m; }
    }

    const size_t o = ((size_t)(n * A_ + a)) * HW_ + cell;   // coalesced per wave
    ws[0 * (size_t)PAIRS + o] = bi;
    ws[1 * (size_t)PAIRS + o] = bu;
    ws[2 * (size_t)PAIRS + o] = ov;
    ws[3 * (size_t)PAIRS + o] = __int_as_float(bm);
}

// ---------------- Kernel B: thread per cell ----------------
// Select best anchor, recompute its box, CE exactly once per cell.
__global__ __launch_bounds__(256) void yolo_cell(
    const float* __restrict__ x,
    const float* __restrict__ anchors,
    const float* __restrict__ gt,
    const int* __restrict__ glab,
    const void* img_h_p, const void* img_w_p,
    float* __restrict__ ws)
{
    const int tid  = threadIdx.x;
    const int n    = blockIdx.y;
    const int cell = blockIdx.x * CPB_B + tid;
    const bool valid = cell < HW_;

    float obj = 0.f, bbx = 0.f, clf = 0.f;

    if (valid) {
        int ibw = *(const int*)img_w_p;
        float img_w = (ibw > 0 && ibw < 1000000) ? (float)ibw : *(const float*)img_w_p;
        int ibh = *(const int*)img_h_p;
        float img_h = (ibh > 0 && ibh < 1000000) ? (float)ibh : *(const float*)img_h_p;
        const float sx = img_w / (float)W_;
        const float sy = img_h / (float)H_;

        const size_t bp = ((size_t)(n * A_)) * HW_ + cell;
        float Bi = 0.f, Bu = 1.f, O = 0.f;
        int Ba = 0, Bm = 0;
        float bomax = -1e30f;
        #pragma unroll
        for (int a = 0; a < A_; ++a) {
            float ci = ws[0 * (size_t)PAIRS + bp + (size_t)a * HW_];
            float cu = ws[1 * (size_t)PAIRS + bp + (size_t)a * HW_];
            float co = ws[2 * (size_t)PAIRS + bp + (size_t)a * HW_];
            bomax = fmaxf(bomax, co);
            bool upd = (a == 0) || (ci * Bu > Bi * cu);
            if (upd) {
                Bi = ci; Bu = cu; O = co; Ba = a;
                Bm = __float_as_int(ws[3 * (size_t)PAIRS + bp + (size_t)a * HW_]);
            }
        }

        if (Bi > 0.f) {
            float d = O - Bi / Bu;
            obj = d * d;

            // recompute winner's box (gathered, <=5 planes, L2/L3-hot)
            const size_t xb = (size_t)n * CH_ * HW_ + (size_t)(Ba * 25) * HW_ + cell;
            float t0 = x[xb];
            float t1 = x[xb + (size_t)HW_];
            float t2 = x[xb + 2 * (size_t)HW_];
            float t3 = x[xb + 3 * (size_t)HW_];
            const int wi = cell % W_;
            const int hi = cell / W_;
            float ax = anchors[2 * Ba];
            float ay = anchors[2 * Ba + 1];
            float bx = 1.f / (1.f + __expf(-t0)) + (float)wi * sx;
            float by = 1.f / (1.f + __expf(-t1)) + (float)hi * sy;
            float bw = sx * ax * __expf(t2);
            float bh = sy * ay * __expf(t3);
            float x1 = bx, y1 = by, x2 = bx + bw, y2 = by + bh;

            float4 g = ((const float4*)gt)[n * M_ + Bm];
            int lab = glab[n * M_ + Bm];
            float d0 = x1 - g.x;
            float d1 = y1 - g.y;
            float d2 = sqrtf(x2) - sqrtf(g.z);
            float d3 = sqrtf(y2) - sqrtf(g.w);
            bbx = d0 * d0 + d1 * d1 + d2 * d2 + d3 * d3;

            // CE once, for the winning anchor only
            float sc[C_];
            #pragma unroll
            for (int j = 0; j < C_; ++j)
                sc[j] = x[xb + (size_t)(5 + j) * HW_];
            float mx = sc[0];
            #pragma unroll
            for (int j = 1; j < C_; ++j) mx = fmaxf(mx, sc[j]);
            float se = 0.f, scl = sc[0];
            #pragma unroll
            for (int j = 0; j < C_; ++j) {
                se += __expf(sc[j] - mx);
                scl = (j == lab) ? sc[j] : scl;
            }
            clf = mx + __logf(se) - scl;
        } else {
            obj = 0.5f * bomax * bomax;
        }
    }

    // block reduce (4 waves)
    #pragma unroll
    for (int off = 32; off > 0; off >>= 1) {
        obj += __shfl_down(obj, off, 64);
        bbx += __shfl_down(bbx, off, 64);
        clf += __shfl_down(clf, off, 64);
    }
    __shared__ float s_red[4][3];
    if ((tid & 63) == 0) {
        const int wid = tid >> 6;
        s_red[wid][0] = obj; s_red[wid][1] = bbx; s_red[wid][2] = clf;
    }
    __syncthreads();
    if (tid == 0) {
        float oo = 0.f, bs = 0.f, cc = 0.f;
        #pragma unroll
        for (int w = 0; w < 4; ++w) {
            oo += s_red[w][0]; bs += s_red[w][1]; cc += s_red[w][2];
        }
        const int bid = blockIdx.y * gridDim.x + blockIdx.x;
        ws[WS_PART + 0 * NBLK_B + bid] = oo;
        ws[WS_PART + 1 * NBLK_B + bid] = bs;
        ws[WS_PART + 2 * NBLK_B + bid] = cc;
    }
}

// ---------------- Kernel C: final reduce ----------------
__global__ __launch_bounds__(1024) void yolo_reduce(
    const float* __restrict__ ws, float* __restrict__ out)
{
    __shared__ float s_red[16][3];
    const int tid = threadIdx.x;
    float o = 0.f, b = 0.f, c = 0.f;
    if (tid < NBLK_B) {
        o = ws[WS_PART + 0 * NBLK_B + tid];
        b = ws[WS_PART + 1 * NBLK_B + tid];
        c = ws[WS_PART + 2 * NBLK_B + tid];
    }
    #pragma unroll
    for (int off = 32; off > 0; off >>= 1) {
        o += __shfl_down(o, off, 64);
        b += __shfl_down(b, off, 64);
        c += __shfl_down(c, off, 64);
    }
    const int wid = tid >> 6;
    if ((tid & 63) == 0) {
        s_red[wid][0] = o; s_red[wid][1] = b; s_red[wid][2] = c;
    }
    __syncthreads();
    if (tid == 0) {
        float oo = 0.f, bb = 0.f, cc = 0.f;
        #pragma unroll
        for (int w = 0; w < 16; ++w) {
            oo += s_red[w][0]; bb += s_red[w][1]; cc += s_red[w][2];
        }
        out[0] = oo; out[1] = bb; out[2] = cc;
    }
}

extern "C" void kernel_launch(void* const* d_in, const int* in_sizes, int n_in,
                              void* d_out, int out_size, void* d_ws, size_t ws_size,
                              hipStream_t stream) {
    (void)in_sizes; (void)n_in; (void)out_size; (void)ws_size;
    const float* x    = (const float*)d_in[0];
    const float* anch = (const float*)d_in[1];
    const float* gt   = (const float*)d_in[2];
    const int*   gl   = (const int*)d_in[3];
    const void*  ih   = d_in[4];
    const void*  iw   = d_in[5];
    float* out = (float*)d_out;
    float* ws  = (float*)d_ws;

    dim3 gridA(NBX_A, N_);
    yolo_pair<<<gridA, dim3(320), 0, stream>>>(x, anch, gt, ih, iw, ws);
    dim3 gridB(NBX_B, N_);
    yolo_cell<<<gridB, dim3(CPB_B), 0, stream>>>(x, anch, gt, gl, ih, iw, ws);
    yolo_reduce<<<1, 1024, 0, stream>>>(ws, out);
}

// Round 5
// 146.898 us; speedup vs baseline: 1.1044x; 1.1044x over previous
//
#include <hip/hip_runtime.h>
#include <math.h>

#define A_ 5
#define C_ 20
#define N_ 64
#define H_ 52
#define W_ 52
#define HW_ (H_ * W_)        // 2704
#define M_ 32
#define CH_ (A_ * (5 + C_))  // 125
#define CPB 128              // cells per block = 64 lanes x 2 cells
#define NBX ((HW_ + CPB - 1) / CPB)   // 22
#define NBLK (NBX * N_)               // 1408

// Block = 320 threads = 5 waves; wave a handles anchor a for 128 cells,
// 2 cells per lane (float2 loads, 512B/wave/inst). 6760 waves total
// (~6.6/SIMD, single-occupancy-round). IoU argmax runs as two independent
// even/odd-m chains (2x critical-path ILP), merged at the end.
__global__ __launch_bounds__(320, 5) void yolo_main(
    const float* __restrict__ x,       // (N, 125, H, W)
    const float* __restrict__ anchors, // (5, 2)
    const float* __restrict__ gt,      // (N, 32, 4)
    const int* __restrict__ glab,      // (N, 32)
    const void* img_h_p, const void* img_w_p,
    float* __restrict__ ws)            // SoA: (3, NBLK)
{
    __shared__ float s_c[5][A_][CPB];  // bi, bu, ov, ce, bb

    const int tid  = threadIdx.x;
    const int a    = tid >> 6;          // anchor = wave id
    const int lane = tid & 63;
    const int n    = blockIdx.y;
    const int cb   = blockIdx.x * CPB + lane * 2;  // first of 2 cells
    const bool valid = cb < HW_;        // HW_ even -> both cells valid together

    int ibw = *(const int*)img_w_p;
    float img_w = (ibw > 0 && ibw < 1000000) ? (float)ibw : *(const float*)img_w_p;
    int ibh = *(const int*)img_h_p;
    float img_h = (ibh > 0 && ibh < 1000000) ? (float)ibh : *(const float*)img_h_p;
    const float sx = img_w / (float)W_;
    const float sy = img_h / (float)H_;

    const float ax = anchors[2 * a];     // wave-uniform
    const float ay = anchors[2 * a + 1];

    float bi[2] = {0.f, 0.f};            // merged results per cell
    float bu[2] = {1.f, 1.f};
    int   bm[2] = {0, 0};
    float ov[2] = {0.f, 0.f};
    float ce[2] = {0.f, 0.f};
    float bb[2] = {0.f, 0.f};

    if (valid) {
        const size_t base = (size_t)n * CH_ * HW_ + (size_t)a * 25 * HW_ + cb;

        // ---- issue all x loads as dwordx2 ----
        float2 T0 = *(const float2*)(x + base);
        float2 T1 = *(const float2*)(x + base + (size_t)HW_);
        float2 T2 = *(const float2*)(x + base + 2 * (size_t)HW_);
        float2 T3 = *(const float2*)(x + base + 3 * (size_t)HW_);
        float2 T4 = *(const float2*)(x + base + 4 * (size_t)HW_);
        float2 S[C_];
        #pragma unroll
        for (int j = 0; j < C_; ++j)
            S[j] = *(const float2*)(x + base + (size_t)(5 + j) * HW_);

        // ---- CE partial (label-independent) first: frees S before IoU ----
        float lse[2];
        {
            const float* Sf = (const float*)S;   // S[j] components j*2+k
            #pragma unroll
            for (int k = 0; k < 2; ++k) {
                float mx = Sf[k];
                #pragma unroll
                for (int j = 1; j < C_; ++j) mx = fmaxf(mx, Sf[j * 2 + k]);
                float se = 0.f;
                #pragma unroll
                for (int j = 0; j < C_; ++j) se += __expf(Sf[j * 2 + k] - mx);
                lse[k] = mx + __logf(se);
            }
        }

        // ---- boxes per cell ----
        float x1[2], y1[2], x2[2], y2[2], ap[2];
        {
            const float* t0 = (const float*)&T0;
            const float* t1 = (const float*)&T1;
            const float* t2 = (const float*)&T2;
            const float* t3 = (const float*)&T3;
            const float* t4 = (const float*)&T4;
            #pragma unroll
            for (int k = 0; k < 2; ++k) {
                const int c  = cb + k;
                const int wi = c % W_;
                const int hi = c / W_;
                float bx = 1.f / (1.f + __expf(-t0[k])) + (float)wi * sx;
                float by = 1.f / (1.f + __expf(-t1[k])) + (float)hi * sy;
                float bw = sx * ax * __expf(t2[k]);
                float bh = sy * ay * __expf(t3[k]);
                x1[k] = bx; y1[k] = by; x2[k] = bx + bw; y2[k] = by + bh;
                ov[k] = 1.f / (1.f + __expf(-t4[k]));
                ap[k] = (x2[k] - x1[k]) * (y2[k] - y1[k]);  // match reference
            }
        }

        // ---- IoU argmax: two independent chains (even/odd m) ----
        float cbi[2][2] = {{0.f, 0.f}, {0.f, 0.f}};   // [cell][chain]
        float cbu[2][2] = {{1.f, 1.f}, {1.f, 1.f}};
        int   cbm[2][2] = {{0, 1}, {0, 1}};
        const float4* gtv = (const float4*)(gt + (size_t)n * M_ * 4);
        #pragma unroll 4
        for (int m = 0; m < M_; m += 2) {
            float4 g0 = gtv[m];       // uniform -> scalar load path
            float4 g1 = gtv[m + 1];
            float ar0 = (g0.z - g0.x) * (g0.w - g0.y);
            float ar1 = (g1.z - g1.x) * (g1.w - g1.y);
            #pragma unroll
            for (int k = 0; k < 2; ++k) {
                {   // chain 0: GT m
                    float wq = fminf(x2[k], g0.z) - fmaxf(x1[k], g0.x);
                    float hq = fminf(y2[k], g0.w) - fmaxf(y1[k], g0.y);
                    wq = fmaxf(wq, 0.f); hq = fmaxf(hq, 0.f);
                    float inter = wq * hq;
                    float uni = ap[k] + ar0 - inter;
                    if (inter * cbu[k][0] > cbi[k][0] * uni) {
                        cbi[k][0] = inter; cbu[k][0] = uni; cbm[k][0] = m;
                    }
                }
                {   // chain 1: GT m+1
                    float wq = fminf(x2[k], g1.z) - fmaxf(x1[k], g1.x);
                    float hq = fminf(y2[k], g1.w) - fmaxf(y1[k], g1.y);
                    wq = fmaxf(wq, 0.f); hq = fmaxf(hq, 0.f);
                    float inter = wq * hq;
                    float uni = ap[k] + ar1 - inter;
                    if (inter * cbu[k][1] > cbi[k][1] * uni) {
                        cbi[k][1] = inter; cbu[k][1] = uni; cbm[k][1] = m + 1;
                    }
                }
            }
        }
        #pragma unroll
        for (int k = 0; k < 2; ++k) {   // merge (tie -> even chain = lower m)
            bool c1 = cbi[k][1] * cbu[k][0] > cbi[k][0] * cbu[k][1];
            bi[k] = c1 ? cbi[k][1] : cbi[k][0];
            bu[k] = c1 ? cbu[k][1] : cbu[k][0];
            bm[k] = c1 ? cbm[k][1] : cbm[k][0];
        }

        // ---- bbox term + CE finish (small gathered, L1/L2-hot) ----
        #pragma unroll
        for (int k = 0; k < 2; ++k) {
            float4 g = ((const float4*)gt)[n * M_ + bm[k]];
            int lab = glab[n * M_ + bm[k]];
            float d0 = x1[k] - g.x;
            float d1 = y1[k] - g.y;
            float d2 = sqrtf(x2[k]) - sqrtf(g.z);
            float d3 = sqrtf(y2[k]) - sqrtf(g.w);
            bb[k] = d0 * d0 + d1 * d1 + d2 * d2 + d3 * d3;
            float sval = x[base + (size_t)(5 + lab) * HW_ + k];  // L2-hot reload
            ce[k] = lse[k] - sval;
        }
    }

    if (valid) {
        const int cl = lane * 2;
        #pragma unroll
        for (int k = 0; k < 2; ++k) {
            s_c[0][a][cl + k] = bi[k];
            s_c[1][a][cl + k] = bu[k];
            s_c[2][a][cl + k] = ov[k];
            s_c[3][a][cl + k] = ce[k];
            s_c[4][a][cl + k] = bb[k];
        }
    }
    __syncthreads();

    // ---- tail: threads 0..127 select best anchor for one cell each ----
    float obj = 0.f, bbx = 0.f, clf = 0.f;
    if (tid < CPB && (blockIdx.x * CPB + tid) < HW_) {
        const int t = tid;
        float Bi = 0.f, Bu = 1.f, O = 0.f, CE = 0.f, BB = 0.f;
        float bomax = -1e30f;
        #pragma unroll
        for (int aa = 0; aa < A_; ++aa) {
            float ci = s_c[0][aa][t];
            float cu = s_c[1][aa][t];
            float co = s_c[2][aa][t];
            bomax = fmaxf(bomax, co);
            bool upd = (aa == 0) || (ci * Bu > Bi * cu);
            if (upd) {
                Bi = ci; Bu = cu; O = co;
                CE = s_c[3][aa][t];
                BB = s_c[4][aa][t];
            }
        }
        if (Bi > 0.f) {
            float d = O - Bi / Bu;
            obj = d * d;
            bbx = BB;
            clf = CE;
        } else {
            obj = 0.5f * bomax * bomax;
        }
    }

    // block reduce across all 5 waves (idle waves contribute zeros)
    #pragma unroll
    for (int off = 32; off > 0; off >>= 1) {
        obj += __shfl_down(obj, off, 64);
        bbx += __shfl_down(bbx, off, 64);
        clf += __shfl_down(clf, off, 64);
    }
    __shared__ float s_red[5][3];
    if ((tid & 63) == 0) {
        const int wid = tid >> 6;
        s_red[wid][0] = obj; s_red[wid][1] = bbx; s_red[wid][2] = clf;
    }
    __syncthreads();
    if (tid == 0) {
        float oo = 0.f, bs = 0.f, cc = 0.f;
        #pragma unroll
        for (int w = 0; w < 5; ++w) {
            oo += s_red[w][0]; bs += s_red[w][1]; cc += s_red[w][2];
        }
        const int bid = blockIdx.y * gridDim.x + blockIdx.x;
        ws[0 * NBLK + bid] = oo;
        ws[1 * NBLK + bid] = bs;
        ws[2 * NBLK + bid] = cc;
    }
}

__global__ __launch_bounds__(1024) void yolo_reduce(
    const float* __restrict__ ws, float* __restrict__ out)
{
    __shared__ float s_red[16][3];
    const int tid = threadIdx.x;
    float o = 0.f, b = 0.f, c = 0.f;
    for (int e = tid; e < NBLK; e += 1024) {
        o += ws[0 * NBLK + e];
        b += ws[1 * NBLK + e];
        c += ws[2 * NBLK + e];
    }
    #pragma unroll
    for (int off = 32; off > 0; off >>= 1) {
        o += __shfl_down(o, off, 64);
        b += __shfl_down(b, off, 64);
        c += __shfl_down(c, off, 64);
    }
    const int wid = tid >> 6;
    if ((tid & 63) == 0) {
        s_red[wid][0] = o; s_red[wid][1] = b; s_red[wid][2] = c;
    }
    __syncthreads();
    if (tid == 0) {
        float oo = 0.f, bb = 0.f, cc = 0.f;
        #pragma unroll
        for (int w = 0; w < 16; ++w) {
            oo += s_red[w][0]; bb += s_red[w][1]; cc += s_red[w][2];
        }
        out[0] = oo; out[1] = bb; out[2] = cc;
    }
}

extern "C" void kernel_launch(void* const* d_in, const int* in_sizes, int n_in,
                              void* d_out, int out_size, void* d_ws, size_t ws_size,
                              hipStream_t stream) {
    (void)in_sizes; (void)n_in; (void)out_size; (void)ws_size;
    const float* x    = (const float*)d_in[0];
    const float* anch = (const float*)d_in[1];
    const float* gt   = (const float*)d_in[2];
    const int*   gl   = (const int*)d_in[3];
    const void*  ih   = d_in[4];
    const void*  iw   = d_in[5];
    float* out = (float*)d_out;
    float* ws  = (float*)d_ws;

    dim3 grid(NBX, N_);
    yolo_main<<<grid, dim3(320), 0, stream>>>(x, anch, gt, gl, ih, iw, ws);
    yolo_reduce<<<1, 1024, 0, stream>>>(ws, out);
}

// Round 6
// 140.964 us; speedup vs baseline: 1.1509x; 1.0421x over previous
//
#include <hip/hip_runtime.h>
#include <math.h>

#define A_ 5
#define C_ 20
#define N_ 64
#define H_ 52
#define W_ 52
#define HW_ (H_ * W_)        // 2704
#define M_ 32
#define CH_ (A_ * (5 + C_))  // 125
#define CPB 64               // cells per block = 64 lanes x 1 cell
#define NBX ((HW_ + CPB - 1) / CPB)   // 43
#define NBLK (NBX * N_)               // 2752

// One thread per CELL owning all 5 anchors. 64-thread (1-wave) blocks:
// no LDS, no barriers, no idle tail waves. 25 coalesced loads up front,
// 5 independent IoU chains in the single m-loop (5-way ILP), winner
// selected in registers, CE computed exactly once (winner anchor only).
__global__ __launch_bounds__(64) void yolo_main(
    const float* __restrict__ x,       // (N, 125, H, W)
    const float* __restrict__ anchors, // (5, 2)
    const float* __restrict__ gt,      // (N, 32, 4)
    const int* __restrict__ glab,      // (N, 32)
    const void* img_h_p, const void* img_w_p,
    float* __restrict__ ws)            // SoA: (3, NBLK)
{
    const int lane = threadIdx.x;
    const int n    = blockIdx.y;
    const int cell = blockIdx.x * CPB + lane;
    const bool valid = cell < HW_;

    int ibw = *(const int*)img_w_p;
    float img_w = (ibw > 0 && ibw < 1000000) ? (float)ibw : *(const float*)img_w_p;
    int ibh = *(const int*)img_h_p;
    float img_h = (ibh > 0 && ibh < 1000000) ? (float)ibh : *(const float*)img_h_p;
    const float sx = img_w / (float)W_;
    const float sy = img_h / (float)H_;

    float obj = 0.f, bbx = 0.f, clf = 0.f;

    if (valid) {
        const size_t base = (size_t)n * CH_ * HW_ + cell;

        // ---- bulk-issue all 25 box-channel loads (coalesced 256B each) ----
        float t[A_][5];
        #pragma unroll
        for (int a = 0; a < A_; ++a)
            #pragma unroll
            for (int v = 0; v < 5; ++v)
                t[a][v] = x[base + (size_t)(a * 25 + v) * HW_];

        const int wi = cell % W_;
        const int hi = cell / W_;

        // ---- 5 boxes in registers ----
        float X1[A_], Y1[A_], X2[A_], Y2[A_], AP[A_], OVv[A_];
        #pragma unroll
        for (int a = 0; a < A_; ++a) {
            float ax = anchors[2 * a];        // uniform scalar loads
            float ay = anchors[2 * a + 1];
            float bx = 1.f / (1.f + __expf(-t[a][0])) + (float)wi * sx;
            float by = 1.f / (1.f + __expf(-t[a][1])) + (float)hi * sy;
            float bw = sx * ax * __expf(t[a][2]);
            float bh = sy * ay * __expf(t[a][3]);
            X1[a] = bx; Y1[a] = by; X2[a] = bx + bw; Y2[a] = by + bh;
            AP[a] = (X2[a] - X1[a]) * (Y2[a] - Y1[a]);   // match reference
            OVv[a] = 1.f / (1.f + __expf(-t[a][4]));
        }

        // ---- single m-loop, 5 independent argmax chains ----
        float BIv[A_] = {0.f, 0.f, 0.f, 0.f, 0.f};
        float BUv[A_] = {1.f, 1.f, 1.f, 1.f, 1.f};
        int   BMv[A_] = {0, 0, 0, 0, 0};
        const float4* gtv = (const float4*)(gt + (size_t)n * M_ * 4);
        #pragma unroll 8
        for (int m = 0; m < M_; ++m) {
            float4 g = gtv[m];                // wave-uniform -> scalar path
            float area = (g.z - g.x) * (g.w - g.y);
            #pragma unroll
            for (int a = 0; a < A_; ++a) {
                float wq = fminf(X2[a], g.z) - fmaxf(X1[a], g.x);
                float hq = fminf(Y2[a], g.w) - fmaxf(Y1[a], g.y);
                wq = fmaxf(wq, 0.f);
                hq = fmaxf(hq, 0.f);
                float inter = wq * hq;
                float uni = AP[a] + area - inter;
                if (inter * BUv[a] > BIv[a] * uni) {
                    BIv[a] = inter; BUv[a] = uni; BMv[a] = m;
                }
            }
        }

        // ---- select winning anchor in registers (first-max semantics) ----
        float Bi = BIv[0], Bu = BUv[0], O = OVv[0];
        float wx1 = X1[0], wy1 = Y1[0], wx2 = X2[0], wy2 = Y2[0];
        int Ba = 0, Bm = BMv[0];
        float bomax = OVv[0];
        #pragma unroll
        for (int a = 1; a < A_; ++a) {
            bomax = fmaxf(bomax, OVv[a]);
            if (BIv[a] * Bu > Bi * BUv[a]) {
                Bi = BIv[a]; Bu = BUv[a]; O = OVv[a];
                wx1 = X1[a]; wy1 = Y1[a]; wx2 = X2[a]; wy2 = Y2[a];
                Ba = a; Bm = BMv[a];
            }
        }

        if (Bi > 0.f) {
            float d = O - Bi / Bu;
            obj = d * d;

            float4 g = ((const float4*)gt)[n * M_ + Bm];
            int lab = glab[n * M_ + Bm];
            float d0 = wx1 - g.x;
            float d1 = wy1 - g.y;
            float d2 = sqrtf(wx2) - sqrtf(g.z);
            float d3 = sqrtf(wy2) - sqrtf(g.w);
            bbx = d0 * d0 + d1 * d1 + d2 * d2 + d3 * d3;

            // ---- CE exactly once: winner's 20 scores (bulk-issued) ----
            const size_t sb = base + (size_t)(Ba * 25 + 5) * HW_;
            float sc[C_];
            #pragma unroll
            for (int j = 0; j < C_; ++j)
                sc[j] = x[sb + (size_t)j * HW_];
            float mx = sc[0];
            #pragma unroll
            for (int j = 1; j < C_; ++j) mx = fmaxf(mx, sc[j]);
            float se = 0.f, scl = sc[0];
            #pragma unroll
            for (int j = 0; j < C_; ++j) {
                se += __expf(sc[j] - mx);
                scl = (j == lab) ? sc[j] : scl;
            }
            clf = mx + __logf(se) - scl;
        } else {
            obj = 0.5f * bomax * bomax;
        }
    }

    // ---- single-wave reduce, one SoA write ----
    #pragma unroll
    for (int off = 32; off > 0; off >>= 1) {
        obj += __shfl_down(obj, off, 64);
        bbx += __shfl_down(bbx, off, 64);
        clf += __shfl_down(clf, off, 64);
    }
    if (lane == 0) {
        const int bid = blockIdx.y * gridDim.x + blockIdx.x;
        ws[0 * NBLK + bid] = obj;
        ws[1 * NBLK + bid] = bbx;
        ws[2 * NBLK + bid] = clf;
    }
}

__global__ __launch_bounds__(1024) void yolo_reduce(
    const float* __restrict__ ws, float* __restrict__ out)
{
    __shared__ float s_red[16][3];
    const int tid = threadIdx.x;
    float o = 0.f, b = 0.f, c = 0.f;
    for (int e = tid; e < NBLK; e += 1024) {
        o += ws[0 * NBLK + e];
        b += ws[1 * NBLK + e];
        c += ws[2 * NBLK + e];
    }
    #pragma unroll
    for (int off = 32; off > 0; off >>= 1) {
        o += __shfl_down(o, off, 64);
        b += __shfl_down(b, off, 64);
        c += __shfl_down(c, off, 64);
    }
    const int wid = tid >> 6;
    if ((tid & 63) == 0) {
        s_red[wid][0] = o; s_red[wid][1] = b; s_red[wid][2] = c;
    }
    __syncthreads();
    if (tid == 0) {
        float oo = 0.f, bb = 0.f, cc = 0.f;
        #pragma unroll
        for (int w = 0; w < 16; ++w) {
            oo += s_red[w][0]; bb += s_red[w][1]; cc += s_red[w][2];
        }
        out[0] = oo; out[1] = bb; out[2] = cc;
    }
}

extern "C" void kernel_launch(void* const* d_in, const int* in_sizes, int n_in,
                              void* d_out, int out_size, void* d_ws, size_t ws_size,
                              hipStream_t stream) {
    (void)in_sizes; (void)n_in; (void)out_size; (void)ws_size;
    const float* x    = (const float*)d_in[0];
    const float* anch = (const float*)d_in[1];
    const float* gt   = (const float*)d_in[2];
    const int*   gl   = (const int*)d_in[3];
    const void*  ih   = d_in[4];
    const void*  iw   = d_in[5];
    float* out = (float*)d_out;
    float* ws  = (float*)d_ws;

    dim3 grid(NBX, N_);
    yolo_main<<<grid, dim3(64), 0, stream>>>(x, anch, gt, gl, ih, iw, ws);
    yolo_reduce<<<1, 1024, 0, stream>>>(ws, out);
}